// Round 1
// baseline (204.931 us; speedup 1.0000x reference)
//
#include <hip/hip_runtime.h>

#define BATCH   1024
#define IN      1024
#define OUT     40960
#define KF      7
#define BT      8            // batch rows per block (4 row-pair regions)
#define NO      4            // output columns per thread
#define THREADS 256
#define OTILE   (THREADS * NO)   // 1024 outputs per block

// y[b, o] = sum_k vals[o,k] * x[b, idx[o,k]]
//
// LDS layout: 4 row-pair regions, 8 KB apart:
//   xs[p*2048 + i*2 + r] = x[b0 + 2*p + r][i],  p in {0..3}, r in {0,1}
// Gather granule is 8 B (ds_read_b64) -> bank group = i & 15 (16 groups),
// vs the old 16 B granule's i & 7 (8 groups). With random i across 64
// lanes this cuts the expected bank conflict from ~8-way (~2.9x, m136)
// to ~4-way (~1.6x), dropping the LDS pipe from ~65us to ~35us.
// The 4 region bases are compile-time byte offsets (0/8192/16384/24576),
// so each (o,k) costs 1 shift + 4 ds_read_b64 with offset immediates.
__global__ __launch_bounds__(THREADS, 4)
void sparse_proj(const float* __restrict__ x, const float* __restrict__ vals,
                 const int* __restrict__ idx, float* __restrict__ y)
{
    __shared__ float xs[4 * IN * 2];   // 32 KB -> LDS allows 5 blocks/CU

    const int t     = threadIdx.x;
    const int b0    = blockIdx.y * BT;
    const int obase = blockIdx.x * OTILE + t;

    // ---- stage x tile (8 rows x 1024 cols) into LDS, pair-interleaved ----
    // Wave w builds region p=w (rows b0+2p, b0+2p+1). Lanes have consecutive
    // i -> both global loads coalesced; ds_write_b64 at dword addr 2i is a
    // 4-way conflict (1.6x) but staging is only ~600 cyc/block.
    {
        const int p  = t >> 6;          // 0..3 (one wave per row pair)
        const int i0 = t & 63;
        const float* xr0 = x + (size_t)(b0 + 2 * p) * IN;
        const float* xr1 = xr0 + IN;
        float* dst = &xs[p * (IN * 2)];
#pragma unroll
        for (int j = 0; j < 16; ++j) {
            const int i = i0 + j * 64;
            float2 f;
            f.x = xr0[i];
            f.y = xr1[i];
            *(float2*)&dst[i * 2] = f;
        }
    }
    __syncthreads();

    float acc[NO][BT];
#pragma unroll
    for (int no = 0; no < NO; ++no)
#pragma unroll
        for (int r = 0; r < BT; ++r) acc[no][r] = 0.0f;

#pragma unroll
    for (int no = 0; no < NO; ++no) {
        const int o = obase + no * THREADS;
        const int*   ip = idx  + (size_t)o * KF;
        const float* vp = vals + (size_t)o * KF;
#pragma unroll
        for (int k = 0; k < KF; ++k) {
            const int   i = ip[k];          // L2-resident (2.3 MB total)
            const float v = vp[k];
            const float2 a0 = *(const float2*)&xs[0 * (IN * 2) + i * 2]; // rows b0+0,1
            const float2 a1 = *(const float2*)&xs[1 * (IN * 2) + i * 2]; // rows b0+2,3
            const float2 a2 = *(const float2*)&xs[2 * (IN * 2) + i * 2]; // rows b0+4,5
            const float2 a3 = *(const float2*)&xs[3 * (IN * 2) + i * 2]; // rows b0+6,7
            acc[no][0] = fmaf(v, a0.x, acc[no][0]);
            acc[no][1] = fmaf(v, a0.y, acc[no][1]);
            acc[no][2] = fmaf(v, a1.x, acc[no][2]);
            acc[no][3] = fmaf(v, a1.y, acc[no][3]);
            acc[no][4] = fmaf(v, a2.x, acc[no][4]);
            acc[no][5] = fmaf(v, a2.y, acc[no][5]);
            acc[no][6] = fmaf(v, a3.x, acc[no][6]);
            acc[no][7] = fmaf(v, a3.y, acc[no][7]);
        }
    }

    // ---- store: coalesced per (row, no); nontemporal so the 168 MB write
    // stream does not evict L2-resident x / idx / vals ----
#pragma unroll
    for (int r = 0; r < BT; ++r) {
        float* yr = y + (size_t)(b0 + r) * OUT;
#pragma unroll
        for (int no = 0; no < NO; ++no) {
            __builtin_nontemporal_store(acc[no][r], &yr[obase + no * THREADS]);
        }
    }
}

extern "C" void kernel_launch(void* const* d_in, const int* in_sizes, int n_in,
                              void* d_out, int out_size, void* d_ws, size_t ws_size,
                              hipStream_t stream) {
    const float* x    = (const float*)d_in[0];   // [1024, 1024] fp32
    const float* vals = (const float*)d_in[1];   // [40960, 7]  fp32
    const int*   idx  = (const int*)d_in[2];     // [40960, 7]  int32
    float*       y    = (float*)d_out;           // [1024, 40960] fp32

    dim3 grid(OUT / OTILE, BATCH / BT);          // (40, 128) = 5120 blocks
    sparse_proj<<<grid, dim3(THREADS), 0, stream>>>(x, vals, idx, y);
}

// Round 2
// 188.123 us; speedup vs baseline: 1.0893x; 1.0893x over previous
//
#include <hip/hip_runtime.h>
#include <hip/hip_fp16.h>

#define BATCH   1024
#define IN      1024
#define OUT     40960
#define KF      7
#define BT      8            // batch rows per block: ALL 8 in one fp16 granule
#define NO      4            // output columns per thread
#define THREADS 256
#define OTILE   (THREADS * NO)   // 1024 outputs per block

// y[b, o] = sum_k vals[o,k] * x[b, idx[o,k]]
//
// Calibrated model (round 0 vs 1): a divergent wave64 ds_read_b128 gather
// costs ~38 cyc (vs 12 conflict-free); the gather was ~71 of ~90 us of
// kernel time, and granule-size changes cannot help (address entropy is
// fixed, 16-B alignment pins granules to 8 bank-quadruples).
// Fix: store x in LDS as fp16, 8 rows per 16-B granule:
//   xs[i*8 + r] = (half)x[b0 + r][i]
// so ONE ds_read_b128 at i*16 yields all 8 batch rows -> gather instruction
// count halves (56 -> 28 per thread), same divergence statistics.
// Accumulation stays fp32 via v_fma_mix (half source, float acc); x rounded
// RTN: worst-case |err| <= 7 * 4.9 * 2^-11 ~= 0.017 < 0.03125 tolerance.
__device__ __forceinline__ float half2_bits(__half2 h) {
    union { __half2 h; float f; } u; u.h = h; return u.f;
}

__global__ __launch_bounds__(THREADS, 4)
void sparse_proj(const float* __restrict__ x, const float* __restrict__ vals,
                 const int* __restrict__ idx, float* __restrict__ y)
{
    __shared__ __align__(16) __half xs[IN * BT];   // 16 KB

    const int t     = threadIdx.x;
    const int b0    = blockIdx.y * BT;
    const int obase = blockIdx.x * OTILE + t;

    // ---- stage x tile (8 rows x 1024 cols) into LDS as fp16 ----
    // Each thread handles 4 columns; per column: 8 coalesced global loads
    // (lanes have consecutive i), 8 RTN cvts, one contiguous ds_write_b128.
    {
        const float* xb = x + (size_t)b0 * IN;
#pragma unroll
        for (int j = 0; j < 4; ++j) {
            const int i = t + j * THREADS;
            __half2 p0, p1, p2, p3;
            p0.x = __float2half_rn(xb[0 * IN + i]);
            p0.y = __float2half_rn(xb[1 * IN + i]);
            p1.x = __float2half_rn(xb[2 * IN + i]);
            p1.y = __float2half_rn(xb[3 * IN + i]);
            p2.x = __float2half_rn(xb[4 * IN + i]);
            p2.y = __float2half_rn(xb[5 * IN + i]);
            p3.x = __float2half_rn(xb[6 * IN + i]);
            p3.y = __float2half_rn(xb[7 * IN + i]);
            float4 f;
            f.x = half2_bits(p0);
            f.y = half2_bits(p1);
            f.z = half2_bits(p2);
            f.w = half2_bits(p3);
            *(float4*)&xs[i * 8] = f;
        }
    }
    __syncthreads();

    float acc[NO][BT];
#pragma unroll
    for (int no = 0; no < NO; ++no)
#pragma unroll
        for (int r = 0; r < BT; ++r) acc[no][r] = 0.0f;

#pragma unroll
    for (int no = 0; no < NO; ++no) {
        const int o = obase + no * THREADS;
        const int*   ip = idx  + (size_t)o * KF;
        const float* vp = vals + (size_t)o * KF;
#pragma unroll
        for (int k = 0; k < KF; ++k) {
            const int   i = ip[k];          // L2-resident (2.3 MB total)
            const float v = vp[k];
            const float4 g = *(const float4*)&xs[i * 8];   // 8 rows, one b128
            const __half2 h0 = *(const __half2*)&g.x;
            const __half2 h1 = *(const __half2*)&g.y;
            const __half2 h2 = *(const __half2*)&g.z;
            const __half2 h3 = *(const __half2*)&g.w;
            acc[no][0] = fmaf(v, __low2float(h0),  acc[no][0]);
            acc[no][1] = fmaf(v, __high2float(h0), acc[no][1]);
            acc[no][2] = fmaf(v, __low2float(h1),  acc[no][2]);
            acc[no][3] = fmaf(v, __high2float(h1), acc[no][3]);
            acc[no][4] = fmaf(v, __low2float(h2),  acc[no][4]);
            acc[no][5] = fmaf(v, __high2float(h2), acc[no][5]);
            acc[no][6] = fmaf(v, __low2float(h3),  acc[no][6]);
            acc[no][7] = fmaf(v, __high2float(h3), acc[no][7]);
        }
    }

    // ---- store: coalesced per (row, no); nontemporal so the 168 MB write
    // stream does not evict L2-resident x / idx / vals ----
#pragma unroll
    for (int r = 0; r < BT; ++r) {
        float* yr = y + (size_t)(b0 + r) * OUT;
#pragma unroll
        for (int no = 0; no < NO; ++no) {
            __builtin_nontemporal_store(acc[no][r], &yr[obase + no * THREADS]);
        }
    }
}

extern "C" void kernel_launch(void* const* d_in, const int* in_sizes, int n_in,
                              void* d_out, int out_size, void* d_ws, size_t ws_size,
                              hipStream_t stream) {
    const float* x    = (const float*)d_in[0];   // [1024, 1024] fp32
    const float* vals = (const float*)d_in[1];   // [40960, 7]  fp32
    const int*   idx  = (const int*)d_in[2];     // [40960, 7]  int32
    float*       y    = (float*)d_out;           // [1024, 40960] fp32

    dim3 grid(OUT / OTILE, BATCH / BT);          // (40, 128) = 5120 blocks
    sparse_proj<<<grid, dim3(THREADS), 0, stream>>>(x, vals, idx, y);
}

// Round 3
// 177.361 us; speedup vs baseline: 1.1554x; 1.0607x over previous
//
#include <hip/hip_runtime.h>
#include <hip/hip_fp16.h>

#define BATCH   1024
#define IN      1024
#define OUT     40960
#define KF      7
#define BT      8            // batch rows per block: all 8 in one fp16 granule
#define NO      4            // output columns per thread
#define THREADS 256
#define OTILE   (THREADS * NO)   // 1024 outputs per block
#define CHUNKS  (OUT / 64)       // 640 chunks of 64 consecutive outputs

// Workspace layout (repacked once per launch by repack_kernel):
//   pvals : f32 [CHUNKS][KF][64]   vals transposed so lane l of chunk c reads
//                                  pvals[c][k][l] with 4-B lane stride (coalesced)
//   xpk   : f16 [BATCH/8][IN][8]   x rounded to fp16, 8 batch rows per 16-B granule
//   pidx  : u16 [CHUNKS][KF][64]   idx<<4 = LDS BYTE offset (i*16), coalesced
#define PV_BYTES  ((size_t)CHUNKS * KF * 64 * 4)          // 1,146,880
#define XPK_BYTES ((size_t)(BATCH / 8) * IN * 8 * 2)      // 2,097,152
#define PIDX_BYTES ((size_t)CHUNKS * KF * 64 * 2)         //   573,440
// total ~3.65 MB of d_ws

// Model calibration (rounds 0/1/2): kernel time = F + c*LDS_instrs with
// F ~= 80 us, c*L0 ~= 10 us. The LDS gather was NEVER the bottleneck; the
// dominant term is the idx/vals global loads, whose 28-B lane stride makes
// every wave-load touch ~28 cache lines (vs 4 coalesced). This version
// repacks idx/vals into lane-major [chunk][k][64] layout so all metadata
// loads are coalesced, and pre-converts x to fp16 in gather layout so the
// main kernel's staging is a straight 16 KB copy.

__global__ __launch_bounds__(THREADS)
void repack_kernel(const float* __restrict__ x, const float* __restrict__ vals,
                   const int* __restrict__ idx,
                   float* __restrict__ pvals, __half* __restrict__ xpk,
                   unsigned short* __restrict__ pidx)
{
    const int gid = blockIdx.x * THREADS + threadIdx.x;
    if (blockIdx.x < 512) {
        // ---- part A: x[1024][1024] f32 -> xpk[g][i][8] f16 ----
        const int g = gid >> 10;        // batch group 0..127
        const int i = gid & 1023;       // column
        const float* xb = x + (size_t)g * 8 * IN + i;
        union { __half h[8]; float4 f; } u;
#pragma unroll
        for (int r = 0; r < 8; ++r) u.h[r] = __float2half_rn(xb[(size_t)r * IN]);
        *(float4*)&xpk[(size_t)gid * 8] = u.f;   // coalesced 16-B store
    } else {
        // ---- part B: idx/vals [OUT][KF] -> [CHUNKS][KF][64] ----
        const int t2 = gid - 512 * THREADS;      // 0 .. 286719
        const int c  = t2 / (KF * 64);
        const int r  = t2 % (KF * 64);
        const int k  = r >> 6;
        const int l  = r & 63;
        const size_t src = (size_t)(c * 64 + l) * KF + k;
        pvals[t2] = vals[src];
        pidx[t2]  = (unsigned short)(idx[src] << 4);   // byte offset into xs
    }
}

__global__ __launch_bounds__(THREADS, 4)
void sparse_proj(const float* __restrict__ pvals, const __half* __restrict__ xpk,
                 const unsigned short* __restrict__ pidx, float* __restrict__ y)
{
    __shared__ __align__(16) __half xs[IN * BT];   // 16 KB: xs[i*8 + r]

    const int t     = threadIdx.x;
    const int b0    = blockIdx.y * BT;
    const int obase = blockIdx.x * OTILE + t;

    // ---- stage: straight 16 KB copy, already fp16 + gather-layout ----
    {
        const float4* src = (const float4*)(xpk + (size_t)blockIdx.y * IN * 8);
        float4* dst = (float4*)xs;
#pragma unroll
        for (int r = 0; r < 4; ++r) dst[t + r * THREADS] = src[t + r * THREADS];
    }
    __syncthreads();

    float acc[NO][BT];
#pragma unroll
    for (int no = 0; no < NO; ++no)
#pragma unroll
        for (int r = 0; r < BT; ++r) acc[no][r] = 0.0f;

    const int w    = t >> 6;
    const int lane = t & 63;

#pragma unroll
    for (int no = 0; no < NO; ++no) {
        // chunk c owns outputs [c*64, c*64+64); this thread's o = c*64 + lane
        // = blockIdx.x*1024 + no*256 + t  (matches the store below)
        const int c = blockIdx.x * 16 + no * 4 + w;
        const unsigned short* ipp = pidx  + (size_t)c * (KF * 64) + lane;
        const float*          vpp = pvals + (size_t)c * (KF * 64) + lane;
#pragma unroll
        for (int k = 0; k < KF; ++k) {
            const unsigned off = ipp[k * 64];   // i*16: coalesced u16 load
            const float v      = vpp[k * 64];   // coalesced f32 load
            const float4 g = *(const float4*)((const char*)xs + off); // 8 rows
            const __half2 h0 = *(const __half2*)&g.x;
            const __half2 h1 = *(const __half2*)&g.y;
            const __half2 h2 = *(const __half2*)&g.z;
            const __half2 h3 = *(const __half2*)&g.w;
            acc[no][0] = fmaf(v, __low2float(h0),  acc[no][0]);
            acc[no][1] = fmaf(v, __high2float(h0), acc[no][1]);
            acc[no][2] = fmaf(v, __low2float(h1),  acc[no][2]);
            acc[no][3] = fmaf(v, __high2float(h1), acc[no][3]);
            acc[no][4] = fmaf(v, __low2float(h2),  acc[no][4]);
            acc[no][5] = fmaf(v, __high2float(h2), acc[no][5]);
            acc[no][6] = fmaf(v, __low2float(h3),  acc[no][6]);
            acc[no][7] = fmaf(v, __high2float(h3), acc[no][7]);
        }
    }

    // ---- store: coalesced per (row, no); nontemporal so the 168 MB write
    // stream does not evict L2-resident xpk / pidx / pvals ----
#pragma unroll
    for (int r = 0; r < BT; ++r) {
        float* yr = y + (size_t)(b0 + r) * OUT;
#pragma unroll
        for (int no = 0; no < NO; ++no) {
            __builtin_nontemporal_store(acc[no][r], &yr[obase + no * THREADS]);
        }
    }
}

extern "C" void kernel_launch(void* const* d_in, const int* in_sizes, int n_in,
                              void* d_out, int out_size, void* d_ws, size_t ws_size,
                              hipStream_t stream) {
    const float* x    = (const float*)d_in[0];   // [1024, 1024] fp32
    const float* vals = (const float*)d_in[1];   // [40960, 7]  fp32
    const int*   idx  = (const int*)d_in[2];     // [40960, 7]  int32
    float*       y    = (float*)d_out;           // [1024, 40960] fp32

    float*          pvals = (float*)d_ws;
    __half*         xpk   = (__half*)((char*)d_ws + PV_BYTES);
    unsigned short* pidx  = (unsigned short*)((char*)d_ws + PV_BYTES + XPK_BYTES);

    // 512 blocks for xpk (131072 threads) + 1120 blocks for idx/vals (286720)
    repack_kernel<<<dim3(512 + 1120), dim3(THREADS), 0, stream>>>(
        x, vals, idx, pvals, xpk, pidx);

    dim3 grid(OUT / OTILE, BATCH / BT);          // (40, 128) = 5120 blocks
    sparse_proj<<<grid, dim3(THREADS), 0, stream>>>(pvals, xpk, pidx, y);
}